// Round 14
// baseline (143.885 us; speedup 1.0000x reference)
//
#include <hip/hip_runtime.h>

#define SS 1024
#define BB 4096
#define HH 8
#define XSTRIDE (BB * HH)   // floats per timestep slice

// DPP cross-lane (VALU pipe). quad_perm xor1/2/3; row_half_mirror (s^7);
// row_ror:8 (s^8 within each 16-lane row).
__device__ __forceinline__ int dpp_x1(int v) { return __builtin_amdgcn_mov_dpp(v, 0xB1, 0xF, 0xF, true); }
__device__ __forceinline__ int dpp_x2(int v) { return __builtin_amdgcn_mov_dpp(v, 0x4E, 0xF, 0xF, true); }
__device__ __forceinline__ int dpp_x3(int v) { return __builtin_amdgcn_mov_dpp(v, 0x1B, 0xF, 0xF, true); }
__device__ __forceinline__ int dpp_x7(int v) { return __builtin_amdgcn_mov_dpp(v, 0x141, 0xF, 0xF, true); }
__device__ __forceinline__ int dpp_r8(int v) { return __builtin_amdgcn_mov_dpp(v, 0x128, 0xF, 0xF, true); }

// Pinned distributed load: 4B/lane (element e0 of this lane's batch).
#define ALOADD(DST, PTR) asm volatile("global_load_dword %0, %1, off" : "=v"(DST) : "v"(PTR))

#define WAITV(N) do {                                                                  \
    asm volatile("s_waitcnt vmcnt(" #N ")" ::: "memory");                              \
    __builtin_amdgcn_sched_barrier(0);                                                 \
} while (0)

// Full X pre-activation for step V (PROLOGUE ONLY now -- the steady state
// computes all X inside the rolling weave). Lane covers 4 columns {e0^0..e0^3};
// partner (s^8) covers the complementary 4; combine via row_ror:8.
#define XFULL(BUF, V) do {                                                             \
    const float va = BUF[V];                                                           \
    const int vai = __float_as_int(va);                                                \
    const float vb = __int_as_float(dpp_x1(vai));                                      \
    const float vc = __int_as_float(dpp_x2(vai));                                      \
    const float vd = __int_as_float(dpp_x3(vai));                                      \
    float sr0 = fmaf(va, wri[0], bias_rx); sr0 = fmaf(vb, wri[1], sr0);                \
    float sr1 = vc * wri[2];               sr1 = fmaf(vd, wri[3], sr1);                \
    float sz0 = fmaf(va, wzi[0], bias_zx); sz0 = fmaf(vb, wzi[1], sz0);                \
    float sz1 = vc * wzi[2];               sz1 = fmaf(vd, wzi[3], sz1);                \
    float sn0 = fmaf(va, wni[0], bias_nx); sn0 = fmaf(vb, wni[1], sn0);                \
    float sn1 = vc * wni[2];               sn1 = fmaf(vd, wni[3], sn1);                \
    const float srt = sr0 + sr1, szt = sz0 + sz1, snt = sn0 + sn1;                     \
    xr[V] = srt + __int_as_float(dpp_r8(__float_as_int(srt)));                         \
    xz[V] = szt + __int_as_float(dpp_r8(__float_as_int(szt)));                         \
    xn[V] = snt + __int_as_float(dpp_r8(__float_as_int(snt)));                         \
} while (0)

// One 8-step group with ROLLING X weave: step u weaves X((u+2)&7); steps 6,7
// weave the NEXT group's X(0),X(1) from NBUF (loaded one group ago; a single
// WAITV(6) at u==6 retires its loads -- expected zero actual wait).
// TAIL=1 (final group): steps 6,7 have no weave.
#define GROUP(BUF, NBUF, SBASE, TAIL) do {                                             \
    _Pragma("unroll")                                                                  \
    for (int u = 0; u < 8; ++u) {                                                      \
        /* h-dots: 12 FMA over this lane's 4 columns */                                \
        const int hvi = __float_as_int(hv);                                            \
        const float ha = hv;                                                           \
        const float hbv = __int_as_float(dpp_x1(hvi));                                 \
        const float hc = __int_as_float(dpp_x2(hvi));                                  \
        const float hd = __int_as_float(dpp_x3(hvi));                                  \
        float pr0 = ha * wrh[0];               pr0 = fmaf(hbv, wrh[1], pr0);           \
        float pr1 = hc * wrh[2];               pr1 = fmaf(hd, wrh[3], pr1);            \
        float pz0 = ha * wzh[0];               pz0 = fmaf(hbv, wzh[1], pz0);           \
        float pz1 = hc * wzh[2];               pz1 = fmaf(hd, wzh[3], pz1);            \
        float pn0 = fmaf(ha, wnh[0], bias_nh); pn0 = fmaf(hbv, wnh[1], pn0);           \
        float pn1 = hc * wnh[2];               pn1 = fmaf(hd, wnh[3], pn1);            \
        const float prt = pr0 + pr1, pzt = pz0 + pz1, pnt = pn0 + pn1;                 \
        const float srr = xr[u] + (prt + __int_as_float(dpp_r8(__float_as_int(prt)))); \
        const float szz = xz[u] + (pzt + __int_as_float(dpp_r8(__float_as_int(pzt)))); \
        const float snn = pnt + __int_as_float(dpp_r8(__float_as_int(pnt)));           \
        const bool W = (!(TAIL)) || (u + 2 < 8);                                       \
        const int slot = (u + 2) & 7;                                                  \
        float wsr0, wsr1, wsz0, wsz1, wsn0, wsn1;                                      \
        float wvc, wvd;                                                                \
        if ((u == 6) && !(TAIL)) WAITV(6);   /* retire NBUF's 8 loads */               \
        if (W) {   /* weave slice 1: dpp reads + first half chains */                  \
            const float va2 = (u + 2 < 8) ? BUF[(u + 2) & 7] : NBUF[u - 6];            \
            const int va2i = __float_as_int(va2);                                      \
            const float vb2 = __int_as_float(dpp_x1(va2i));                            \
            wvc = __int_as_float(dpp_x2(va2i));                                        \
            wvd = __int_as_float(dpp_x3(va2i));                                        \
            wsr0 = fmaf(va2, wri[0], bias_rx); wsr0 = fmaf(vb2, wri[1], wsr0);         \
            wsz0 = fmaf(va2, wzi[0], bias_zx); wsz0 = fmaf(vb2, wzi[1], wsz0);         \
            wsn0 = fmaf(va2, wni[0], bias_nx); wsn0 = fmaf(vb2, wni[1], wsn0);         \
        }                                                                              \
        const float er = __builtin_amdgcn_exp2f(srr);                                  \
        const float ez = __builtin_amdgcn_exp2f(szz);                                  \
        if (W) {   /* weave slice 2: second half chains */                             \
            wsr1 = wvc * wri[2]; wsr1 = fmaf(wvd, wri[3], wsr1);                       \
            wsz1 = wvc * wzi[2]; wsz1 = fmaf(wvd, wzi[3], wsz1);                       \
            wsn1 = wvc * wni[2]; wsn1 = fmaf(wvd, wni[3], wsn1);                       \
        }                                                                              \
        const float r_ = __builtin_amdgcn_rcpf(1.0f + er);                             \
        const float z_ = __builtin_amdgcn_rcpf(1.0f + ez);                             \
        if (W) {   /* weave slice 3: combine + stage into rolling slot */              \
            const float srt = wsr0 + wsr1, szt = wsz0 + wsz1, snt = wsn0 + wsn1;       \
            xr[slot] = srt + __int_as_float(dpp_r8(__float_as_int(srt)));              \
            xz[slot] = szt + __int_as_float(dpp_r8(__float_as_int(szt)));              \
            xn[slot] = snt + __int_as_float(dpp_r8(__float_as_int(snt)));              \
        }                                                                              \
        const float en = __builtin_amdgcn_exp2f(fmaf(r_, snn, xn[u]));                 \
        const float n_ = fmaf(-2.0f, __builtin_amdgcn_rcpf(1.0f + en), 1.0f);          \
        h = n_ + z_ * (h - n_);                                                        \
        /* rebuild skewed replica: upper half needs h from lane s^4 */                 \
        const int hbits = __float_as_int(h);                                           \
        const int tA = dpp_x7(hbits);                                                  \
        const int tB = dpp_x3(tA);                                                     \
        hv = hiHalf ? __int_as_float(tB) : h;                                          \
        __builtin_nontemporal_store(h, &op[(size_t)((SBASE) + u) * XSTRIDE]);          \
    }                                                                                  \
} while (0)

// 8 pinned dword loads = one 8-step group (1 per step per lane).
#define LOADG(BUF, GRP) do {                                                           \
    const float* bp_ = xq + (size_t)(GRP) * 8 * XSTRIDE;                               \
    _Pragma("unroll")                                                                  \
    for (int u_ = 0; u_ < 8; ++u_) ALOADD(BUF[u_], bp_ + (size_t)u_ * XSTRIDE);        \
} while (0)

// 16 lanes per batch element (row j = s&7, column-half = s>>3), 4 batches per
// wave, 1024 waves = 1 wave per SIMD.
__global__ __launch_bounds__(64, 1) void gru_kernel(
    const float* __restrict__ x,
    const float* __restrict__ w_ih,
    const float* __restrict__ w_hh,
    const float* __restrict__ b_ih,
    const float* __restrict__ b_hh,
    float* __restrict__ out)
{
    const int lane = threadIdx.x;
    const int s16 = lane & 15;
    const int j = s16 & 7;
    const int half = s16 >> 3;
    const bool hiHalf = (half != 0);
    const int e0 = j ^ (half << 2);        // element replica this lane holds

    const float SR = -1.4426950408889634f; // -log2(e): sigmoid scale
    const float SN = 2.8853900817779268f;  // 2*log2(e): tanh scale

    // Weights for row j over this lane's 4 columns e0^m (pre-scaled).
    float wri[4], wzi[4], wni[4], wrh[4], wzh[4], wnh[4];
    #pragma unroll
    for (int m = 0; m < 4; ++m) {
        const int c = e0 ^ m;
        wri[m] = SR * w_ih[j * 8 + c];
        wzi[m] = SR * w_ih[(8 + j) * 8 + c];
        wni[m] = SN * w_ih[(16 + j) * 8 + c];
        wrh[m] = SR * w_hh[j * 8 + c];
        wzh[m] = SR * w_hh[(8 + j) * 8 + c];
        wnh[m] = SN * w_hh[(16 + j) * 8 + c];
    }
    // Biases live only in the lower-half partials (combine adds them once).
    const float bias_rx = hiHalf ? 0.0f : SR * (b_ih[j] + b_hh[j]);
    const float bias_zx = hiHalf ? 0.0f : SR * (b_ih[8 + j] + b_hh[8 + j]);
    const float bias_nx = hiHalf ? 0.0f : SN * b_ih[16 + j];
    const float bias_nh = hiHalf ? 0.0f : SN * b_hh[16 + j];

    // Addresses: batch bg = blockIdx*4 + (lane>>4). Loads fetch element e0
    // (skewed replica); stores write row j (dup across halves, same value).
    const float* xq = x + (blockIdx.x << 5) + ((lane >> 4) << 3) + e0;
    float* op = out + (blockIdx.x << 5) + ((lane >> 4) << 3) + j;
    float* hlast = out + (size_t)SS * BB * HH + (blockIdx.x << 5) + ((lane >> 4) << 3) + j;

    float xA[8], xB[8];   // distributed x: 1 dword/lane/step

    // prologue: groups 0 -> A, 1 -> B; retire A's 8 (B's 8 stay in flight)
    LOADG(xA, 0);
    LOADG(xB, 1);
    WAITV(8);

    float h = 0.0f;
    float hv = 0.0f;      // skewed replica of h (h[e0])
    float xr[8], xz[8], xn[8];

    // Prologue X for group 0 steps 0,1 (the only XFULL calls; all later X
    // values come from the rolling weave).
    XFULL(xA, 0);
    XFULL(xA, 1);

    // Pipeline: GROUP's internal WAITV(6) at u==6 does all load/compute sync.
    // Steady outstanding at u==6: [8 old stores, 8 NBUF loads, 6 stores]=22;
    // WAITV(6) retires the oldest 16.
    for (int g = 0; g < 124; g += 2) {
        GROUP(xA, xB, g * 8, 0);
        LOADG(xA, g + 2);
        GROUP(xB, xA, (g + 1) * 8, 0);
        LOADG(xB, g + 3);
    }
    GROUP(xA, xB, 992, 0);  LOADG(xA, 126);   // weaves B[125]... X roll into g125
    GROUP(xB, xA, 1000, 0); LOADG(xB, 127);
    GROUP(xA, xB, 1008, 0);                   // weaves xB (group 127) X(0),X(1)
    GROUP(xB, xA, 1016, 1);                   // TAIL: no weave at steps 6,7

    *hlast = h;
}

extern "C" void kernel_launch(void* const* d_in, const int* in_sizes, int n_in,
                              void* d_out, int out_size, void* d_ws, size_t ws_size,
                              hipStream_t stream) {
    const float* x    = (const float*)d_in[0];
    const float* w_ih = (const float*)d_in[1];
    const float* w_hh = (const float*)d_in[2];
    const float* b_ih = (const float*)d_in[3];
    const float* b_hh = (const float*)d_in[4];
    float* out = (float*)d_out;
    gru_kernel<<<BB / 4, 64, 0, stream>>>(x, w_ih, w_hh, b_ih, b_hh, out);
}